// Round 11
// baseline (396.096 us; speedup 1.0000x reference)
//
#include <hip/hip_runtime.h>

#define N_NODES 20000
#define N_PAD   20032            // 313 * 64
#define N_EDGES 200000
#define ETOT    (N_EDGES + N_NODES)
#define F_IN    20
#define HID     128
#define HEADS   4
#define FTOT    (HEADS * HID)   // 512
#define LAYERS  4
#define NGRAPH  32
#define NEG_SLOPE 0.2f
#define DEG_CAP 64

typedef __attribute__((ext_vector_type(8))) unsigned short ushortx8;
typedef __attribute__((ext_vector_type(8))) short short8;
typedef __attribute__((ext_vector_type(4))) float f32x4;

static __device__ __forceinline__ unsigned short f2bf(float f) {
    unsigned u = __float_as_uint(f);
    u += 0x7FFFu + ((u >> 16) & 1u);   // round-to-nearest-even
    return (unsigned short)(u >> 16);
}
static __device__ __forceinline__ float bf2f(unsigned short s) {
    return __uint_as_float(((unsigned)s) << 16);
}

// ---------------- CSR build + graph bounds (fused) ----------------

__global__ void k_histb(const int* __restrict__ ei, const int* __restrict__ batch,
                        int* __restrict__ deg, int* __restrict__ gstart) {
    int i = blockIdx.x * blockDim.x + threadIdx.x;
    if (i < ETOT) {
        int d = (i < N_EDGES) ? ei[N_EDGES + i] : (i - N_EDGES);
        atomicAdd(&deg[d], 1);
    }
    if (i < N_NODES) {
        int b = batch[i];
        int prev = (i == 0) ? -1 : batch[i - 1];
        for (int g = prev + 1; g <= b; ++g) gstart[g] = i;
        if (i == N_NODES - 1) {
            for (int g = b + 1; g <= NGRAPH; ++g) gstart[g] = N_NODES;
        }
    }
}

__global__ __launch_bounds__(1024) void k_scan(const int* __restrict__ deg, int* __restrict__ off) {
    __shared__ int wsum[16];
    __shared__ int carry_s;
    int tid  = threadIdx.x;
    int lane = tid & 63, wv = tid >> 6;
    if (tid == 0) carry_s = 0;
    __syncthreads();
    for (int base = 0; base < N_NODES; base += 1024) {
        int idx = base + tid;
        int v = (idx < N_NODES) ? deg[idx] : 0;
        int x = v;
        #pragma unroll
        for (int s = 1; s < 64; s <<= 1) {
            int t = __shfl_up(x, s, 64);
            if (lane >= s) x += t;
        }
        if (lane == 63) wsum[wv] = x;
        __syncthreads();
        if (wv == 0) {
            int ws = (lane < 16) ? wsum[lane] : 0;
            #pragma unroll
            for (int s = 1; s < 16; s <<= 1) {
                int t = __shfl_up(ws, s, 64);
                if (lane >= s) ws += t;
            }
            if (lane < 16) wsum[lane] = ws;
        }
        __syncthreads();
        int wprev = (wv == 0) ? 0 : wsum[wv - 1];
        int incl  = carry_s + wprev + x;
        if (idx < N_NODES) off[idx] = incl - v;
        __syncthreads();
        if (tid == 1023) carry_s = incl;
        __syncthreads();
    }
    if (threadIdx.x == 0) off[N_NODES] = carry_s;
}

__global__ void k_scatter(const int* __restrict__ ei, const int* __restrict__ off,
                          int* __restrict__ cur, int* __restrict__ csr_src) {
    int i = blockIdx.x * blockDim.x + threadIdx.x;
    if (i >= ETOT) return;
    int s, d;
    if (i < N_EDGES) { s = ei[i]; d = ei[N_EDGES + i]; }
    else             { s = d = i - N_EDGES; }
    int pos = off[d] + atomicAdd(&cur[d], 1);
    csr_src[pos] = s;
}

// ---------------- weight prep ----------------
// Wstack[ks=hd*128+j][c] = gat_W[l][j][hd*128+c], in MFMA B-fragment order:
// [l][cg(8)][kc(16)][lane(64)][e(8)], value = Wstack[kc*32+(lane>>4)*8+e][cg*16+(lane&15)]

__global__ void k_wconv(const float* __restrict__ W, unsigned short* __restrict__ wswz) {
    int o = blockIdx.x * 256 + threadIdx.x;
    if (o >= LAYERS * 8 * 16 * 64 * 8) return;
    int e    = o & 7;
    int lane = (o >> 3) & 63;
    int kc   = (o >> 9) & 15;
    int cg   = (o >> 13) & 7;
    int l    = o >> 16;
    int ks   = kc * 32 + (lane >> 4) * 8 + e;   // 0..511
    int c    = cg * 16 + (lane & 15);           // 0..127
    int j    = ks & 127, hd = ks >> 7;
    wswz[o] = f2bf(W[((size_t)l * HID + j) * FTOT + hd * HID + c]);
}

// wa[l][sd][h][j] = sum_c gat_W[l][j][h*128+c] * (sd? adst : asrc)[l][h][c]

__global__ void k_wa(const float* __restrict__ W, const float* __restrict__ asrc,
                     const float* __restrict__ adst, float* __restrict__ wa) {
    int t = blockIdx.x * 256 + threadIdx.x;
    if (t >= LAYERS * 2 * HEADS * HID) return;
    int j  = t & 127;
    int h  = (t >> 7) & 3;
    int sd = (t >> 9) & 1;
    int l  = t >> 10;
    const float* a    = (sd ? adst : asrc) + ((size_t)l * HEADS + h) * HID;
    const float* Wrow = W + ((size_t)l * HID + j) * FTOT + h * HID;
    float s = 0.f;
    #pragma unroll 4
    for (int c = 0; c < HID; ++c) s += Wrow[c] * a[c];
    wa[t] = s;
}

// ---------------- input projection: h = relu(x @ W_in + b_in), + bf16 shadow ----------------

__global__ __launch_bounds__(256) void k_inproj(const float* __restrict__ x,
                                                const float* __restrict__ W,
                                                const float* __restrict__ b,
                                                float* __restrict__ h,
                                                unsigned short* __restrict__ hb) {
    __shared__ float xs[2][F_IN];
    int tid = threadIdx.x;
    int node0 = blockIdx.x * 2;
    if (tid < 2 * F_IN) {
        int r = tid / F_IN, k = tid % F_IN;
        int nd = node0 + r;
        xs[r][k] = (nd < N_NODES) ? x[nd * F_IN + k] : 0.f;
    }
    __syncthreads();
    int ln = tid >> 7;
    int c  = tid & 127;
    int node = node0 + ln;
    if (node >= N_NODES) return;
    float s = b[c];
    #pragma unroll
    for (int k = 0; k < F_IN; ++k) s += xs[ln][k] * W[k * HID + c];
    float r = fmaxf(s, 0.f);
    h[(size_t)node * HID + c] = r;
    hb[(size_t)node * HID + c] = f2bf(r);
}

// ---------------- attention logits: al[n,h] = hb[n,:] . wa[h,:] ----------------
// 8 threads per node (4 heads x {src,dst}); 32 nodes/block.

__global__ __launch_bounds__(256) void k_att(const unsigned short* __restrict__ hb,
                                             const float* __restrict__ wa,
                                             float* __restrict__ al_s,
                                             float* __restrict__ al_d) {
    __shared__ float wl[2 * HEADS * HID];   // 4 KB
    int tid = threadIdx.x;
    for (int i = tid; i < 2 * HEADS * HID; i += 256) wl[i] = wa[i];
    __syncthreads();
    int nl = tid >> 3;
    int h  = tid & 3;
    int sd = (tid >> 2) & 1;
    int node = blockIdx.x * 32 + nl;
    const unsigned short* row = hb + (size_t)node * HID;
    const float* w = wl + (sd * HEADS + h) * HID;
    float s = 0.f;
    #pragma unroll
    for (int j0 = 0; j0 < HID; j0 += 8) {
        ushortx8 v = *(const ushortx8*)(row + j0);
        #pragma unroll
        for (int e = 0; e < 8; ++e) s += bf2f(v[e]) * w[j0 + e];
    }
    if (sd == 0) al_s[node * HEADS + h] = s;
    else         al_d[node * HEADS + h] = s;
}

// ---------------- edge aggregation in h-space ----------------
// 1 wave/node. Pass A: per-head (m,z) + alpha->LDS (as R9). Pass B: gather
// hb[src] (256B/edge, 4B/lane = 2ch), 4 heads x 2ch FMA; no epilogue shuffles.
// Output u[n, hd*128+j] = zinv_hd * sum_s alpha * h_s[j]  (bf16).

__global__ __launch_bounds__(256) void k_agg(const unsigned short* __restrict__ hb,
                                             const float* __restrict__ al_s,
                                             const float* __restrict__ al_d,
                                             const int* __restrict__ csr_off,
                                             const int* __restrict__ csr_src,
                                             unsigned short* __restrict__ u) {
    __shared__ float alds[4][DEG_CAP][HEADS];   // 4 KB
    __shared__ float zlds[4][HEADS];
    __shared__ float mlds[4][HEADS];
    int tid  = threadIdx.x;
    int lane = tid & 63;
    int wid  = tid >> 6;
    int node = blockIdx.x * 4 + wid;            // grid exact: 5000*4 = 20000
    int hh = lane >> 4;
    int el = lane & 15;
    int e0 = csr_off[node], e1 = csr_off[node + 1];
    int deg = e1 - e0;
    float ald = al_d[node * HEADS + hh];

    // ---- pass A ----
    float ev0 = -1e30f, ev1 = -1e30f, ev2 = -1e30f, ev3 = -1e30f;
    if (el < deg) {
        int s = csr_src[e0 + el];
        float e = al_s[s * HEADS + hh] + ald;
        ev0 = e > 0.f ? e : NEG_SLOPE * e;
    }
    if (el + 16 < deg) {
        int s = csr_src[e0 + el + 16];
        float e = al_s[s * HEADS + hh] + ald;
        ev1 = e > 0.f ? e : NEG_SLOPE * e;
    }
    if (el + 32 < deg) {
        int s = csr_src[e0 + el + 32];
        float e = al_s[s * HEADS + hh] + ald;
        ev2 = e > 0.f ? e : NEG_SLOPE * e;
    }
    if (el + 48 < deg) {
        int s = csr_src[e0 + el + 48];
        float e = al_s[s * HEADS + hh] + ald;
        ev3 = e > 0.f ? e : NEG_SLOPE * e;
    }
    float m = fmaxf(fmaxf(ev0, ev1), fmaxf(ev2, ev3));
    float z = 0.f;
    if (el      < deg) z += __expf(ev0 - m);
    if (el + 16 < deg) z += __expf(ev1 - m);
    if (el + 32 < deg) z += __expf(ev2 - m);
    if (el + 48 < deg) z += __expf(ev3 - m);
    for (int i = el + DEG_CAP; i < deg; i += 16) {   // rare tail
        int s = csr_src[e0 + i];
        float e = al_s[s * HEADS + hh] + ald;
        e = e > 0.f ? e : NEG_SLOPE * e;
        float mn = fmaxf(m, e);
        z = z * __expf(m - mn) + __expf(e - mn);
        m = mn;
    }
    #pragma unroll
    for (int msk = 1; msk < 16; msk <<= 1) {
        float m2 = __shfl_xor(m, msk, 64);
        float z2 = __shfl_xor(z, msk, 64);
        float mn = fmaxf(m, m2);
        z = z * __expf(m - mn) + z2 * __expf(m2 - mn);
        m = mn;
    }
    if (el == 0) {
        zlds[wid][hh] = 1.f / (z + 1e-16f);
        mlds[wid][hh] = m;
    }
    if (el      < deg) alds[wid][el     ][hh] = __expf(ev0 - m);
    if (el + 16 < deg) alds[wid][el + 16][hh] = __expf(ev1 - m);
    if (el + 32 < deg) alds[wid][el + 32][hh] = __expf(ev2 - m);
    if (el + 48 < deg) alds[wid][el + 48][hh] = __expf(ev3 - m);
    __syncthreads();

    // ---- pass B: gather hb rows, 2 channels/lane, all 4 heads ----
    float a0c0 = 0.f, a1c0 = 0.f, a2c0 = 0.f, a3c0 = 0.f;
    float a0c1 = 0.f, a1c1 = 0.f, a2c1 = 0.f, a3c1 = 0.f;
    const unsigned short* xbase = hb + lane * 2;
    int dcap = deg < DEG_CAP ? deg : DEG_CAP;
    int i = 0;
    for (; i + 1 < dcap; i += 2) {
        int s0 = csr_src[e0 + i];
        int s1 = csr_src[e0 + i + 1];
        unsigned w0 = *(const unsigned*)(xbase + (size_t)s0 * HID);
        unsigned w1 = *(const unsigned*)(xbase + (size_t)s1 * HID);
        f32x4 p0 = *(const f32x4*)&alds[wid][i][0];
        f32x4 p1 = *(const f32x4*)&alds[wid][i + 1][0];
        float c00 = bf2f((unsigned short)w0), c01 = bf2f((unsigned short)(w0 >> 16));
        float c10 = bf2f((unsigned short)w1), c11 = bf2f((unsigned short)(w1 >> 16));
        a0c0 += p0[0] * c00 + p1[0] * c10;  a0c1 += p0[0] * c01 + p1[0] * c11;
        a1c0 += p0[1] * c00 + p1[1] * c10;  a1c1 += p0[1] * c01 + p1[1] * c11;
        a2c0 += p0[2] * c00 + p1[2] * c10;  a2c1 += p0[2] * c01 + p1[2] * c11;
        a3c0 += p0[3] * c00 + p1[3] * c10;  a3c1 += p0[3] * c01 + p1[3] * c11;
    }
    if (i < dcap) {
        int s0 = csr_src[e0 + i];
        unsigned w0 = *(const unsigned*)(xbase + (size_t)s0 * HID);
        f32x4 p0 = *(const f32x4*)&alds[wid][i][0];
        float c00 = bf2f((unsigned short)w0), c01 = bf2f((unsigned short)(w0 >> 16));
        a0c0 += p0[0] * c00;  a0c1 += p0[0] * c01;
        a1c0 += p0[1] * c00;  a1c1 += p0[1] * c01;
        a2c0 += p0[2] * c00;  a2c1 += p0[2] * c01;
        a3c0 += p0[3] * c00;  a3c1 += p0[3] * c01;
    }
    if (deg > DEG_CAP) {                        // rare tail (never for this graph)
        f32x4 ald4 = *(const f32x4*)&al_d[node * HEADS];
        f32x4 m4;
        m4[0] = mlds[wid][0]; m4[1] = mlds[wid][1];
        m4[2] = mlds[wid][2]; m4[3] = mlds[wid][3];
        for (int t = DEG_CAP; t < deg; ++t) {
            int s0 = csr_src[e0 + t];
            unsigned w0 = *(const unsigned*)(xbase + (size_t)s0 * HID);
            float c00 = bf2f((unsigned short)w0), c01 = bf2f((unsigned short)(w0 >> 16));
            #pragma unroll
            for (int hd = 0; hd < 4; ++hd) {
                float e = al_s[s0 * HEADS + hd] + ald4[hd];
                e = e > 0.f ? e : NEG_SLOPE * e;
                float p = __expf(e - m4[hd]);
                if (hd == 0) { a0c0 += p * c00; a0c1 += p * c01; }
                if (hd == 1) { a1c0 += p * c00; a1c1 += p * c01; }
                if (hd == 2) { a2c0 += p * c00; a2c1 += p * c01; }
                if (hd == 3) { a3c0 += p * c00; a3c1 += p * c01; }
            }
        }
    }
    f32x4 zi = *(const f32x4*)&zlds[wid][0];
    unsigned short* ubase = u + (size_t)node * FTOT + lane * 2;
    {
        unsigned pk0 = (unsigned)f2bf(a0c0 * zi[0]) | ((unsigned)f2bf(a0c1 * zi[0]) << 16);
        unsigned pk1 = (unsigned)f2bf(a1c0 * zi[1]) | ((unsigned)f2bf(a1c1 * zi[1]) << 16);
        unsigned pk2 = (unsigned)f2bf(a2c0 * zi[2]) | ((unsigned)f2bf(a2c1 * zi[2]) << 16);
        unsigned pk3 = (unsigned)f2bf(a3c0 * zi[3]) | ((unsigned)f2bf(a3c1 * zi[3]) << 16);
        *(unsigned*)(ubase)             = pk0;
        *(unsigned*)(ubase + HID)       = pk1;
        *(unsigned*)(ubase + 2 * HID)   = pk2;
        *(unsigned*)(ubase + 3 * HID)   = pk3;
    }
}

// ---------------- GEMM2 (MFMA, K=512): h_new = relu(0.25*(u @ Wstack) + b) + h ----------------
// grid N_PAD/64; block 256 = 4 waves; wave w: rows [bx*64+w*16,+16), cols 0..127.

__global__ __launch_bounds__(256) void k_gemm2(const unsigned short* __restrict__ u,
                                               const unsigned short* __restrict__ wswz,
                                               const float* __restrict__ bias,
                                               float* __restrict__ h,
                                               unsigned short* __restrict__ hb) {
    int tid  = threadIdx.x;
    int lane = tid & 63;
    int w    = tid >> 6;
    int r0   = blockIdx.x * 64 + w * 16;
    int arow = r0 + (lane & 15);
    const short8* ap = (const short8*)(u + (size_t)arow * FTOT + (lane >> 4) * 8);
    const short8* bp = (const short8*)wswz;
    short8 a[16];
    #pragma unroll
    for (int kc = 0; kc < 16; ++kc) a[kc] = ap[kc * 4];   // kc*32 shorts
    f32x4 acc[8];
    #pragma unroll
    for (int cg = 0; cg < 8; ++cg) {
        f32x4 c = {0.f, 0.f, 0.f, 0.f};
        #pragma unroll
        for (int kc = 0; kc < 16; ++kc) {
            c = __builtin_amdgcn_mfma_f32_16x16x32_bf16(a[kc], bp[(cg * 16 + kc) * 64 + lane], c, 0, 0, 0);
        }
        acc[cg] = c;
    }
    int ocol = lane & 15;
    int orow = r0 + (lane >> 4) * 4;
    #pragma unroll
    for (int cg = 0; cg < 8; ++cg) {
        int col = cg * 16 + ocol;
        float bv = bias[col];
        #pragma unroll
        for (int r = 0; r < 4; ++r) {
            int row = orow + r;
            if (row < N_NODES) {
                size_t idx = (size_t)row * HID + col;
                float val = fmaxf(acc[cg][r] * 0.25f + bv, 0.f) + h[idx];
                h[idx] = val;
                hb[idx] = f2bf(val);
            }
        }
    }
}

// ---------------- pooling + MLP ----------------

__global__ __launch_bounds__(128) void k_pool(const float* __restrict__ h,
                                              const int* __restrict__ gstart,
                                              float* __restrict__ pooled) {
    int g = blockIdx.y;
    int slice = blockIdx.x;      // 0..31
    int tid = threadIdx.x;       // 0..127
    int start = gstart[g];
    int cnt   = gstart[g + 1] - start;
    int per = (cnt + 31) / 32;
    int r0 = slice * per, r1 = min(r0 + per, cnt);
    if (r0 >= r1) return;
    float s0 = 0.f, s1 = 0.f, s2 = 0.f, s3 = 0.f;
    int r = r0;
    for (; r + 3 < r1; r += 4) {
        s0 += h[(size_t)(start + r)     * HID + tid];
        s1 += h[(size_t)(start + r + 1) * HID + tid];
        s2 += h[(size_t)(start + r + 2) * HID + tid];
        s3 += h[(size_t)(start + r + 3) * HID + tid];
    }
    for (; r < r1; ++r) s0 += h[(size_t)(start + r) * HID + tid];
    atomicAdd(&pooled[g * HID + tid], (s0 + s1) + (s2 + s3));
}

__global__ __launch_bounds__(256) void k_mlp(const float* __restrict__ pooled,
                                             const int* __restrict__ gstart,
                                             const float* __restrict__ W1, const float* __restrict__ b1,
                                             const float* __restrict__ W2, const float* __restrict__ b2,
                                             const float* __restrict__ W3, const float* __restrict__ b3,
                                             float* __restrict__ out) {
    int gr = blockIdx.x;
    __shared__ float g[HID];
    __shared__ float part[4][64];
    __shared__ float t1[64], t2[64];
    int tid = threadIdx.x;
    if (tid < HID) {
        float inv = 1.f / fmaxf((float)(gstart[gr + 1] - gstart[gr]), 1.f);
        g[tid] = pooled[gr * HID + tid] * inv;
    }
    __syncthreads();
    {
        int c = tid & 63, q = tid >> 6;
        float s = 0.f;
        #pragma unroll 8
        for (int k = q * 32; k < q * 32 + 32; ++k) s += g[k] * W1[k * 64 + c];
        part[q][c] = s;
        __syncthreads();
        if (tid < 64) t1[tid] = fmaxf(part[0][tid] + part[1][tid] + part[2][tid] + part[3][tid] + b1[tid], 0.f);
        __syncthreads();
    }
    {
        int c = tid & 63, q = tid >> 6;
        float s = 0.f;
        #pragma unroll 8
        for (int k = q * 16; k < q * 16 + 16; ++k) s += t1[k] * W2[k * 64 + c];
        part[q][c] = s;
        __syncthreads();
        if (tid < 64) t2[tid] = fmaxf(part[0][tid] + part[1][tid] + part[2][tid] + part[3][tid] + b2[tid], 0.f);
        __syncthreads();
    }
    {
        int c = tid & 31, q = tid >> 5;
        float s = 0.f;
        #pragma unroll 8
        for (int k = q * 8; k < q * 8 + 8; ++k) s += t2[k] * W3[k * 32 + c];
        float* pf = &part[0][0];
        pf[q * 32 + c] = s;
        __syncthreads();
        if (tid < 32) {
            float r = b3[tid];
            #pragma unroll
            for (int q2 = 0; q2 < 8; ++q2) r += pf[q2 * 32 + tid];
            out[gr * 32 + tid] = r;
        }
    }
}

// ---------------- launcher ----------------

extern "C" void kernel_launch(void* const* d_in, const int* in_sizes, int n_in,
                              void* d_out, int out_size, void* d_ws, size_t ws_size,
                              hipStream_t stream) {
    const float* x       = (const float*)d_in[0];
    const int*   ei      = (const int*)d_in[1];
    const int*   batch   = (const int*)d_in[2];
    const float* W_in    = (const float*)d_in[3];
    const float* b_in    = (const float*)d_in[4];
    const float* gat_W   = (const float*)d_in[5];
    const float* att_src = (const float*)d_in[6];
    const float* att_dst = (const float*)d_in[7];
    const float* gat_b   = (const float*)d_in[8];
    const float* W1 = (const float*)d_in[9];
    const float* b1 = (const float*)d_in[10];
    const float* W2 = (const float*)d_in[11];
    const float* b2 = (const float*)d_in[12];
    const float* W3 = (const float*)d_in[13];
    const float* b3 = (const float*)d_in[14];
    float* out = (float*)d_out;

    char* ws = (char*)d_ws;
    size_t o = 0;
    auto alloc = [&](size_t nbytes) -> void* {
        void* p = ws + o;
        o += (nbytes + 255) & ~(size_t)255;
        return p;
    };
    // one contiguous zeroed region: deg | cur | pooled
    int* zero_rgn = (int*)alloc((size_t)(2 * N_NODES + NGRAPH * HID) * 4);
    int* deg      = zero_rgn;
    int* cur      = deg + N_NODES;
    float* pooled = (float*)(cur + N_NODES);
    int* gstart   = (int*)alloc((size_t)(NGRAPH + 1) * 4);
    int* csr_off  = (int*)alloc((size_t)(N_NODES + 1) * 4);
    int* csr_src  = (int*)alloc((size_t)ETOT * 4);
    float* h      = (float*)alloc((size_t)N_NODES * HID * 4);
    unsigned short* hb   = (unsigned short*)alloc((size_t)N_PAD * HID * 2);
    unsigned short* uagg = (unsigned short*)alloc((size_t)N_PAD * FTOT * 2);
    unsigned short* wswz = (unsigned short*)alloc((size_t)LAYERS * FTOT * HID * 2);
    float* wa     = (float*)alloc((size_t)LAYERS * 2 * HEADS * HID * 4);
    float* al_s   = (float*)alloc((size_t)N_NODES * HEADS * 4);
    float* al_d   = (float*)alloc((size_t)N_NODES * HEADS * 4);

    hipMemsetAsync(zero_rgn, 0, (size_t)(2 * N_NODES + NGRAPH * HID) * 4, stream);

    k_histb<<<(ETOT + 255) / 256, 256, 0, stream>>>(ei, batch, deg, gstart);
    k_scan<<<1, 1024, 0, stream>>>(deg, csr_off);
    k_scatter<<<(ETOT + 255) / 256, 256, 0, stream>>>(ei, csr_off, cur, csr_src);
    k_wconv<<<(LAYERS * 8 * 16 * 64 * 8) / 256, 256, 0, stream>>>(gat_W, wswz);
    k_wa<<<(LAYERS * 2 * HEADS * HID + 255) / 256, 256, 0, stream>>>(gat_W, att_src, att_dst, wa);

    k_inproj<<<(N_NODES + 1) / 2, 256, 0, stream>>>(x, W_in, b_in, h, hb);

    for (int l = 0; l < LAYERS; ++l) {
        k_att<<<N_NODES / 32, 256, 0, stream>>>(
            hb, wa + (size_t)l * 2 * HEADS * HID, al_s, al_d);
        k_agg<<<N_NODES / 4, 256, 0, stream>>>(
            hb, al_s, al_d, csr_off, csr_src, uagg);
        k_gemm2<<<N_PAD / 64, 256, 0, stream>>>(
            uagg, wswz + (size_t)l * FTOT * HID, gat_b + (size_t)l * HID, h, hb);
    }

    k_pool<<<dim3(32, NGRAPH), 128, 0, stream>>>(h, gstart, pooled);
    k_mlp<<<NGRAPH, 256, 0, stream>>>(pooled, gstart, W1, b1, W2, b2, W3, b3, out);
}

// Round 12
// 384.577 us; speedup vs baseline: 1.0300x; 1.0300x over previous
//
#include <hip/hip_runtime.h>

#define N_NODES 20000
#define N_PAD   20032            // 313 * 64
#define N_EDGES 200000
#define ETOT    (N_EDGES + N_NODES)
#define F_IN    20
#define HID     128
#define HEADS   4
#define FTOT    (HEADS * HID)   // 512
#define LAYERS  4
#define NGRAPH  32
#define NEG_SLOPE 0.2f
#define DEG_CAP 64

typedef __attribute__((ext_vector_type(8))) unsigned short ushortx8;
typedef __attribute__((ext_vector_type(8))) short short8;
typedef __attribute__((ext_vector_type(4))) float f32x4;

static __device__ __forceinline__ unsigned short f2bf(float f) {
    unsigned u = __float_as_uint(f);
    u += 0x7FFFu + ((u >> 16) & 1u);   // round-to-nearest-even
    return (unsigned short)(u >> 16);
}
static __device__ __forceinline__ float bf2f(unsigned short s) {
    return __uint_as_float(((unsigned)s) << 16);
}

// ---------------- CSR build (dst is layer-invariant) ----------------

__global__ void k_hist(const int* __restrict__ ei, int* __restrict__ deg) {
    int i = blockIdx.x * blockDim.x + threadIdx.x;
    if (i >= ETOT) return;
    int d = (i < N_EDGES) ? ei[N_EDGES + i] : (i - N_EDGES);
    atomicAdd(&deg[d], 1);
}

__global__ __launch_bounds__(1024) void k_scan(const int* __restrict__ deg, int* __restrict__ off) {
    __shared__ int wsum[16];
    __shared__ int carry_s;
    int tid  = threadIdx.x;
    int lane = tid & 63, wv = tid >> 6;
    if (tid == 0) carry_s = 0;
    __syncthreads();
    for (int base = 0; base < N_NODES; base += 1024) {
        int idx = base + tid;
        int v = (idx < N_NODES) ? deg[idx] : 0;
        int x = v;
        #pragma unroll
        for (int s = 1; s < 64; s <<= 1) {
            int t = __shfl_up(x, s, 64);
            if (lane >= s) x += t;
        }
        if (lane == 63) wsum[wv] = x;
        __syncthreads();
        if (wv == 0) {
            int ws = (lane < 16) ? wsum[lane] : 0;
            #pragma unroll
            for (int s = 1; s < 16; s <<= 1) {
                int t = __shfl_up(ws, s, 64);
                if (lane >= s) ws += t;
            }
            if (lane < 16) wsum[lane] = ws;
        }
        __syncthreads();
        int wprev = (wv == 0) ? 0 : wsum[wv - 1];
        int incl  = carry_s + wprev + x;
        if (idx < N_NODES) off[idx] = incl - v;
        __syncthreads();
        if (tid == 1023) carry_s = incl;
        __syncthreads();
    }
    if (threadIdx.x == 0) off[N_NODES] = carry_s;
}

__global__ void k_scatter(const int* __restrict__ ei, const int* __restrict__ off,
                          int* __restrict__ cur, int* __restrict__ csr_src) {
    int i = blockIdx.x * blockDim.x + threadIdx.x;
    if (i >= ETOT) return;
    int s, d;
    if (i < N_EDGES) { s = ei[i]; d = ei[N_EDGES + i]; }
    else             { s = d = i - N_EDGES; }
    int pos = off[d] + atomicAdd(&cur[d], 1);
    csr_src[pos] = s;
}

// ---------------- graph boundaries (batch is sorted): no atomics ----------------

__global__ void k_bounds(const int* __restrict__ batch, int* __restrict__ gstart) {
    int i = blockIdx.x * blockDim.x + threadIdx.x;
    if (i >= N_NODES) return;
    int b = batch[i];
    int prev = (i == 0) ? -1 : batch[i - 1];
    for (int g = prev + 1; g <= b; ++g) gstart[g] = i;
    if (i == N_NODES - 1) {
        for (int g = b + 1; g <= NGRAPH; ++g) gstart[g] = N_NODES;
    }
}

// ---------------- W pre-swizzle: gat_W fp32 -> bf16 MFMA-fragment order ----------------

__global__ void k_wconv(const float* __restrict__ W, unsigned short* __restrict__ wswz) {
    int o = blockIdx.x * 256 + threadIdx.x;
    if (o >= LAYERS * 32 * 4 * 64 * 8) return;
    int e    = o & 7;
    int lane = (o >> 3) & 63;
    int kc   = (o >> 9) & 3;
    int cg   = (o >> 11) & 31;
    int l    = o >> 16;
    int k    = kc * 32 + (lane >> 4) * 8 + e;
    int col  = cg * 16 + (lane & 15);
    wswz[o] = f2bf(W[((size_t)l * HID + k) * FTOT + col]);
}

// ---------------- input projection: h = relu(x @ W_in + b_in), + bf16 shadow ----------------

__global__ __launch_bounds__(256) void k_inproj(const float* __restrict__ x,
                                                const float* __restrict__ W,
                                                const float* __restrict__ b,
                                                float* __restrict__ h,
                                                unsigned short* __restrict__ hb) {
    __shared__ float xs[2][F_IN];
    int tid = threadIdx.x;
    int node0 = blockIdx.x * 2;
    if (tid < 2 * F_IN) {
        int r = tid / F_IN, k = tid % F_IN;
        int nd = node0 + r;
        xs[r][k] = (nd < N_NODES) ? x[nd * F_IN + k] : 0.f;
    }
    __syncthreads();
    int ln = tid >> 7;
    int c  = tid & 127;
    int node = node0 + ln;
    if (node >= N_NODES) return;
    float s = b[c];
    #pragma unroll
    for (int k = 0; k < F_IN; ++k) s += xs[ln][k] * W[k * HID + c];
    float r = fmaxf(s, 0.f);
    h[(size_t)node * HID + c] = r;
    hb[(size_t)node * HID + c] = f2bf(r);
}

// ---------------- GEMM (MFMA) + fused attention dots ----------------
// grid (N_PAD/64, HEADS); block 256 = 4 waves; wave w: rows [bx*64+w*16,+16),
// cols [hd*128, +128). al_s/al_d written by plain stores.

__global__ __launch_bounds__(256) void k_gemm(const unsigned short* __restrict__ hb,
                                              const unsigned short* __restrict__ wswz,
                                              const float* __restrict__ asrc,
                                              const float* __restrict__ adst,
                                              unsigned short* __restrict__ xl,
                                              float* __restrict__ al_s,
                                              float* __restrict__ al_d) {
    int tid  = threadIdx.x;
    int lane = tid & 63;
    int w    = tid >> 6;
    int r0   = blockIdx.x * 64 + w * 16;
    int hd   = blockIdx.y;
    int arow = r0 + (lane & 15);
    const short8* ap = (const short8*)(hb + (size_t)arow * HID + (lane >> 4) * 8);
    const short8* bp = (const short8*)wswz;
    short8 a[4];
    #pragma unroll
    for (int kc = 0; kc < 4; ++kc) a[kc] = ap[kc * 4];   // kc*32 channels
    f32x4 acc[8];
    #pragma unroll
    for (int ct = 0; ct < 8; ++ct) {
        f32x4 c = {0.f, 0.f, 0.f, 0.f};
        int cg = hd * 8 + ct;
        #pragma unroll
        for (int kc = 0; kc < 4; ++kc) {
            short8 b = bp[(cg * 4 + kc) * 64 + lane];
            c = __builtin_amdgcn_mfma_f32_16x16x32_bf16(a[kc], b, c, 0, 0, 0);
        }
        acc[ct] = c;
    }
    int ocol = lane & 15;
    int orow = r0 + (lane >> 4) * 4;
    float vs[4] = {}, vd[4] = {};
    #pragma unroll
    for (int ct = 0; ct < 8; ++ct) {
        int colg = hd * 128 + ct * 16 + ocol;
        float as = asrc[colg], ad = adst[colg];
        #pragma unroll
        for (int r = 0; r < 4; ++r) {
            vs[r] += acc[ct][r] * as;
            vd[r] += acc[ct][r] * ad;
            int row = orow + r;
            if (row < N_NODES) xl[(size_t)row * FTOT + colg] = f2bf(acc[ct][r]);
        }
    }
    #pragma unroll
    for (int msk = 1; msk < 16; msk <<= 1) {
        #pragma unroll
        for (int r = 0; r < 4; ++r) {
            vs[r] += __shfl_xor(vs[r], msk, 64);
            vd[r] += __shfl_xor(vd[r], msk, 64);
        }
    }
    if (ocol == 0) {
        #pragma unroll
        for (int r = 0; r < 4; ++r) {
            int row = orow + r;
            if (row < N_NODES) {
                al_s[row * HEADS + hd] = vs[r];
                al_d[row * HEADS + hd] = vd[r];
            }
        }
    }
}

// ---------------- edge aggregation ----------------
// 512 threads = 8 waves = 4 nodes; TWO waves per node. Even wave does pass A
// (softmax stats + alpha->LDS). Pass B: wave pair splits edges by parity --
// each edge processed once; 2x resident gather-waves vs R9 to raise the
// number of outstanding random 1KB fetches (measured HBM-random-bound).

__global__ __launch_bounds__(512) void k_agg(const unsigned short* __restrict__ xl,
                                             const float* __restrict__ al_s,
                                             const float* __restrict__ al_d,
                                             const int* __restrict__ csr_off,
                                             const int* __restrict__ csr_src,
                                             const float* __restrict__ bias,
                                             float* __restrict__ h,
                                             unsigned short* __restrict__ hb) {
    __shared__ float alds[4][DEG_CAP][HEADS];   // 4 KB
    __shared__ float zin[4][HEADS];
    __shared__ float psum[4][HID];              // 2 KB
    int tid  = threadIdx.x;
    int lane = tid & 63;
    int wid  = tid >> 6;        // 0..7
    int nip  = wid >> 1;        // node within block
    int half = wid & 1;         // edge-parity owned by this wave
    int node = blockIdx.x * 4 + nip;   // grid exact: 5000*4 = 20000
    int hh = lane >> 4;
    int el = lane & 15;
    int e0 = csr_off[node], e1 = csr_off[node + 1];
    int deg = e1 - e0;
    float m_keep = -1e30f;

    if (half == 0) {
        float ald = al_d[node * HEADS + hh];
        float ev0 = -1e30f, ev1 = -1e30f, ev2 = -1e30f, ev3 = -1e30f;
        if (el < deg) {
            int s = csr_src[e0 + el];
            float e = al_s[s * HEADS + hh] + ald;
            ev0 = e > 0.f ? e : NEG_SLOPE * e;
        }
        if (el + 16 < deg) {
            int s = csr_src[e0 + el + 16];
            float e = al_s[s * HEADS + hh] + ald;
            ev1 = e > 0.f ? e : NEG_SLOPE * e;
        }
        if (el + 32 < deg) {
            int s = csr_src[e0 + el + 32];
            float e = al_s[s * HEADS + hh] + ald;
            ev2 = e > 0.f ? e : NEG_SLOPE * e;
        }
        if (el + 48 < deg) {
            int s = csr_src[e0 + el + 48];
            float e = al_s[s * HEADS + hh] + ald;
            ev3 = e > 0.f ? e : NEG_SLOPE * e;
        }
        float m = fmaxf(fmaxf(ev0, ev1), fmaxf(ev2, ev3));
        float z = 0.f;
        if (el      < deg) z += __expf(ev0 - m);
        if (el + 16 < deg) z += __expf(ev1 - m);
        if (el + 32 < deg) z += __expf(ev2 - m);
        if (el + 48 < deg) z += __expf(ev3 - m);
        for (int i = el + DEG_CAP; i < deg; i += 16) {   // rare tail
            int s = csr_src[e0 + i];
            float e = al_s[s * HEADS + hh] + ald;
            e = e > 0.f ? e : NEG_SLOPE * e;
            float mn = fmaxf(m, e);
            z = z * __expf(m - mn) + __expf(e - mn);
            m = mn;
        }
        #pragma unroll
        for (int msk = 1; msk < 16; msk <<= 1) {
            float m2 = __shfl_xor(m, msk, 64);
            float z2 = __shfl_xor(z, msk, 64);
            float mn = fmaxf(m, m2);
            z = z * __expf(m - mn) + z2 * __expf(m2 - mn);
            m = mn;
        }
        if (el == 0) zin[nip][hh] = 1.f / (z + 1e-16f);
        if (el      < deg) alds[nip][el     ][hh] = __expf(ev0 - m);
        if (el + 16 < deg) alds[nip][el + 16][hh] = __expf(ev1 - m);
        if (el + 32 < deg) alds[nip][el + 32][hh] = __expf(ev2 - m);
        if (el + 48 < deg) alds[nip][el + 48][hh] = __expf(ev3 - m);
        m_keep = m;
    }
    __syncthreads();

    // ---- pass B: parity-split gather, 2-unrolled (edges half, half+2, ...) ----
    float acc[8] = {};
    const unsigned short* xbase = xl + lane * 8;
    int dcap = deg < DEG_CAP ? deg : DEG_CAP;
    int i = half;
    for (; i + 2 < dcap; i += 4) {
        int s0 = csr_src[e0 + i];
        int s1 = csr_src[e0 + i + 2];
        float a0 = alds[nip][i][hh];
        float a1 = alds[nip][i + 2][hh];
        ushortx8 v0 = *(const ushortx8*)(xbase + (size_t)s0 * FTOT);
        ushortx8 v1 = *(const ushortx8*)(xbase + (size_t)s1 * FTOT);
        #pragma unroll
        for (int j = 0; j < 8; ++j) acc[j] += a0 * bf2f(v0[j]) + a1 * bf2f(v1[j]);
    }
    if (i < dcap) {
        int s0 = csr_src[e0 + i];
        float a0 = alds[nip][i][hh];
        ushortx8 v0 = *(const ushortx8*)(xbase + (size_t)s0 * FTOT);
        #pragma unroll
        for (int j = 0; j < 8; ++j) acc[j] += a0 * bf2f(v0[j]);
    }
    if (half == 0) {                      // rare tail deg > DEG_CAP (never here)
        float ald = al_d[node * HEADS + hh];
        for (int t = DEG_CAP; t < deg; ++t) {
            int s0 = csr_src[e0 + t];
            float e = al_s[s0 * HEADS + hh] + ald;
            e = e > 0.f ? e : NEG_SLOPE * e;
            float a0 = __expf(e - m_keep);
            ushortx8 v0 = *(const ushortx8*)(xbase + (size_t)s0 * FTOT);
            #pragma unroll
            for (int j = 0; j < 8; ++j) acc[j] += a0 * bf2f(v0[j]);
        }
    }
    // normalize + head-mean reduce within wave (lanes l, l^16, l^32, l^48)
    float zv = zin[nip][hh];
    #pragma unroll
    for (int j = 0; j < 8; ++j) {
        acc[j] *= zv;
        acc[j] += __shfl_xor(acc[j], 16, 64);
        acc[j] += __shfl_xor(acc[j], 32, 64);
    }
    // combine the two parity-waves via LDS
    if (half == 1 && lane < 16) {
        int c = lane * 8;
        float4 p0 = make_float4(acc[0], acc[1], acc[2], acc[3]);
        float4 p1 = make_float4(acc[4], acc[5], acc[6], acc[7]);
        *(float4*)&psum[nip][c]     = p0;
        *(float4*)&psum[nip][c + 4] = p1;
    }
    __syncthreads();
    if (half == 0 && lane < 16) {
        int c = lane * 8;
        float4 q0 = *(const float4*)&psum[nip][c];
        float4 q1 = *(const float4*)&psum[nip][c + 4];
        float4 hv0 = *(const float4*)(h + (size_t)node * HID + c);
        float4 hv1 = *(const float4*)(h + (size_t)node * HID + c + 4);
        float4 b0 = *(const float4*)(bias + c);
        float4 b1 = *(const float4*)(bias + c + 4);
        float o0 = fmaxf((acc[0] + q0.x) * 0.25f + b0.x, 0.f) + hv0.x;
        float o1 = fmaxf((acc[1] + q0.y) * 0.25f + b0.y, 0.f) + hv0.y;
        float o2 = fmaxf((acc[2] + q0.z) * 0.25f + b0.z, 0.f) + hv0.z;
        float o3 = fmaxf((acc[3] + q0.w) * 0.25f + b0.w, 0.f) + hv0.w;
        float o4 = fmaxf((acc[4] + q1.x) * 0.25f + b1.x, 0.f) + hv1.x;
        float o5 = fmaxf((acc[5] + q1.y) * 0.25f + b1.y, 0.f) + hv1.y;
        float o6 = fmaxf((acc[6] + q1.z) * 0.25f + b1.z, 0.f) + hv1.z;
        float o7 = fmaxf((acc[7] + q1.w) * 0.25f + b1.w, 0.f) + hv1.w;
        *(float4*)(h + (size_t)node * HID + c)     = make_float4(o0, o1, o2, o3);
        *(float4*)(h + (size_t)node * HID + c + 4) = make_float4(o4, o5, o6, o7);
        ushortx8 hv;
        hv[0] = f2bf(o0); hv[1] = f2bf(o1); hv[2] = f2bf(o2); hv[3] = f2bf(o3);
        hv[4] = f2bf(o4); hv[5] = f2bf(o5); hv[6] = f2bf(o6); hv[7] = f2bf(o7);
        *(ushortx8*)(hb + (size_t)node * HID + c) = hv;
    }
}

// ---------------- pooling + MLP ----------------

__global__ __launch_bounds__(128) void k_pool(const float* __restrict__ h,
                                              const int* __restrict__ gstart,
                                              float* __restrict__ pooled) {
    int g = blockIdx.y;
    int slice = blockIdx.x;      // 0..31
    int tid = threadIdx.x;       // 0..127
    int start = gstart[g];
    int cnt   = gstart[g + 1] - start;
    int per = (cnt + 31) / 32;
    int r0 = slice * per, r1 = min(r0 + per, cnt);
    if (r0 >= r1) return;
    float s0 = 0.f, s1 = 0.f, s2 = 0.f, s3 = 0.f;
    int r = r0;
    for (; r + 3 < r1; r += 4) {
        s0 += h[(size_t)(start + r)     * HID + tid];
        s1 += h[(size_t)(start + r + 1) * HID + tid];
        s2 += h[(size_t)(start + r + 2) * HID + tid];
        s3 += h[(size_t)(start + r + 3) * HID + tid];
    }
    for (; r < r1; ++r) s0 += h[(size_t)(start + r) * HID + tid];
    atomicAdd(&pooled[g * HID + tid], (s0 + s1) + (s2 + s3));
}

__global__ __launch_bounds__(256) void k_mlp(const float* __restrict__ pooled,
                                             const int* __restrict__ gstart,
                                             const float* __restrict__ W1, const float* __restrict__ b1,
                                             const float* __restrict__ W2, const float* __restrict__ b2,
                                             const float* __restrict__ W3, const float* __restrict__ b3,
                                             float* __restrict__ out) {
    int gr = blockIdx.x;
    __shared__ float g[HID];
    __shared__ float part[4][64];
    __shared__ float t1[64], t2[64];
    int tid = threadIdx.x;
    if (tid < HID) {
        float inv = 1.f / fmaxf((float)(gstart[gr + 1] - gstart[gr]), 1.f);
        g[tid] = pooled[gr * HID + tid] * inv;
    }
    __syncthreads();
    {
        int c = tid & 63, q = tid >> 6;
        float s = 0.f;
        #pragma unroll 8
        for (int k = q * 32; k < q * 32 + 32; ++k) s += g[k] * W1[k * 64 + c];
        part[q][c] = s;
        __syncthreads();
        if (tid < 64) t1[tid] = fmaxf(part[0][tid] + part[1][tid] + part[2][tid] + part[3][tid] + b1[tid], 0.f);
        __syncthreads();
    }
    {
        int c = tid & 63, q = tid >> 6;
        float s = 0.f;
        #pragma unroll 8
        for (int k = q * 16; k < q * 16 + 16; ++k) s += t1[k] * W2[k * 64 + c];
        part[q][c] = s;
        __syncthreads();
        if (tid < 64) t2[tid] = fmaxf(part[0][tid] + part[1][tid] + part[2][tid] + part[3][tid] + b2[tid], 0.f);
        __syncthreads();
    }
    {
        int c = tid & 31, q = tid >> 5;
        float s = 0.f;
        #pragma unroll 8
        for (int k = q * 8; k < q * 8 + 8; ++k) s += t2[k] * W3[k * 32 + c];
        float* pf = &part[0][0];
        pf[q * 32 + c] = s;
        __syncthreads();
        if (tid < 32) {
            float r = b3[tid];
            #pragma unroll
            for (int q2 = 0; q2 < 8; ++q2) r += pf[q2 * 32 + tid];
            out[gr * 32 + tid] = r;
        }
    }
}

// ---------------- launcher ----------------

extern "C" void kernel_launch(void* const* d_in, const int* in_sizes, int n_in,
                              void* d_out, int out_size, void* d_ws, size_t ws_size,
                              hipStream_t stream) {
    const float* x       = (const float*)d_in[0];
    const int*   ei      = (const int*)d_in[1];
    const int*   batch   = (const int*)d_in[2];
    const float* W_in    = (const float*)d_in[3];
    const float* b_in    = (const float*)d_in[4];
    const float* gat_W   = (const float*)d_in[5];
    const float* att_src = (const float*)d_in[6];
    const float* att_dst = (const float*)d_in[7];
    const float* gat_b   = (const float*)d_in[8];
    const float* W1 = (const float*)d_in[9];
    const float* b1 = (const float*)d_in[10];
    const float* W2 = (const float*)d_in[11];
    const float* b2 = (const float*)d_in[12];
    const float* W3 = (const float*)d_in[13];
    const float* b3 = (const float*)d_in[14];
    float* out = (float*)d_out;

    char* ws = (char*)d_ws;
    size_t o = 0;
    auto alloc = [&](size_t nbytes) -> void* {
        void* p = ws + o;
        o += (nbytes + 255) & ~(size_t)255;
        return p;
    };
    int* deg      = (int*)alloc((size_t)2 * N_NODES * 4);      // deg | cur
    int* cur      = deg + N_NODES;
    int* gstart   = (int*)alloc((size_t)(NGRAPH + 1) * 4);
    float* pooled = (float*)alloc((size_t)NGRAPH * HID * 4);
    int* csr_off  = (int*)alloc((size_t)(N_NODES + 1) * 4);
    int* csr_src  = (int*)alloc((size_t)ETOT * 4);
    float* h      = (float*)alloc((size_t)N_NODES * HID * 4);
    unsigned short* hb   = (unsigned short*)alloc((size_t)N_PAD * HID * 2);
    unsigned short* xl   = (unsigned short*)alloc((size_t)N_NODES * FTOT * 2);
    unsigned short* wswz = (unsigned short*)alloc((size_t)LAYERS * HID * FTOT * 2);
    float* al_s   = (float*)alloc((size_t)N_NODES * HEADS * 4);
    float* al_d   = (float*)alloc((size_t)N_NODES * HEADS * 4);

    hipMemsetAsync(deg, 0, (size_t)2 * N_NODES * 4, stream);
    hipMemsetAsync(pooled, 0, (size_t)NGRAPH * HID * 4, stream);

    k_hist<<<(ETOT + 255) / 256, 256, 0, stream>>>(ei, deg);
    k_scan<<<1, 1024, 0, stream>>>(deg, csr_off);
    k_scatter<<<(ETOT + 255) / 256, 256, 0, stream>>>(ei, csr_off, cur, csr_src);
    k_bounds<<<(N_NODES + 255) / 256, 256, 0, stream>>>(batch, gstart);
    k_wconv<<<(LAYERS * 32 * 4 * 64 * 8) / 256, 256, 0, stream>>>(gat_W, wswz);

    k_inproj<<<(N_NODES + 1) / 2, 256, 0, stream>>>(x, W_in, b_in, h, hb);

    for (int l = 0; l < LAYERS; ++l) {
        k_gemm<<<dim3(N_PAD / 64, HEADS), 256, 0, stream>>>(
            hb, wswz + (size_t)l * HID * FTOT,
            att_src + (size_t)l * HEADS * HID, att_dst + (size_t)l * HEADS * HID,
            xl, al_s, al_d);
        k_agg<<<N_NODES / 4, 512, 0, stream>>>(
            xl, al_s, al_d, csr_off, csr_src, gat_b + (size_t)l * HID, h, hb);
    }

    k_pool<<<dim3(32, NGRAPH), 128, 0, stream>>>(h, gstart, pooled);
    k_mlp<<<NGRAPH, 256, 0, stream>>>(pooled, gstart, W1, b1, W2, b2, W3, b3, out);
}

// Round 13
// 370.692 us; speedup vs baseline: 1.0685x; 1.0375x over previous
//
#include <hip/hip_runtime.h>

#define N_NODES 20000
#define N_PAD   20032            // 313 * 64
#define N_EDGES 200000
#define ETOT    (N_EDGES + N_NODES)
#define F_IN    20
#define HID     128
#define HEADS   4
#define FTOT    (HEADS * HID)   // 512
#define LAYERS  4
#define NGRAPH  32
#define NEG_SLOPE 0.2f
#define DEG_CAP 64

typedef __attribute__((ext_vector_type(8))) unsigned short ushortx8;
typedef __attribute__((ext_vector_type(8))) short short8;
typedef __attribute__((ext_vector_type(4))) float f32x4;

static __device__ __forceinline__ unsigned short f2bf(float f) {
    unsigned u = __float_as_uint(f);
    u += 0x7FFFu + ((u >> 16) & 1u);   // round-to-nearest-even
    return (unsigned short)(u >> 16);
}
static __device__ __forceinline__ float bf2f(unsigned short s) {
    return __uint_as_float(((unsigned)s) << 16);
}

// ---------------- CSR build (dst is layer-invariant) ----------------

__global__ void k_hist(const int* __restrict__ ei, int* __restrict__ deg) {
    int i = blockIdx.x * blockDim.x + threadIdx.x;
    if (i >= ETOT) return;
    int d = (i < N_EDGES) ? ei[N_EDGES + i] : (i - N_EDGES);
    atomicAdd(&deg[d], 1);
}

__global__ __launch_bounds__(1024) void k_scan(const int* __restrict__ deg, int* __restrict__ off) {
    __shared__ int wsum[16];
    __shared__ int carry_s;
    int tid  = threadIdx.x;
    int lane = tid & 63, wv = tid >> 6;
    if (tid == 0) carry_s = 0;
    __syncthreads();
    for (int base = 0; base < N_NODES; base += 1024) {
        int idx = base + tid;
        int v = (idx < N_NODES) ? deg[idx] : 0;
        int x = v;
        #pragma unroll
        for (int s = 1; s < 64; s <<= 1) {
            int t = __shfl_up(x, s, 64);
            if (lane >= s) x += t;
        }
        if (lane == 63) wsum[wv] = x;
        __syncthreads();
        if (wv == 0) {
            int ws = (lane < 16) ? wsum[lane] : 0;
            #pragma unroll
            for (int s = 1; s < 16; s <<= 1) {
                int t = __shfl_up(ws, s, 64);
                if (lane >= s) ws += t;
            }
            if (lane < 16) wsum[lane] = ws;
        }
        __syncthreads();
        int wprev = (wv == 0) ? 0 : wsum[wv - 1];
        int incl  = carry_s + wprev + x;
        if (idx < N_NODES) off[idx] = incl - v;
        __syncthreads();
        if (tid == 1023) carry_s = incl;
        __syncthreads();
    }
    if (threadIdx.x == 0) off[N_NODES] = carry_s;
}

__global__ void k_scatter(const int* __restrict__ ei, const int* __restrict__ off,
                          int* __restrict__ cur, int* __restrict__ csr_src) {
    int i = blockIdx.x * blockDim.x + threadIdx.x;
    if (i >= ETOT) return;
    int s, d;
    if (i < N_EDGES) { s = ei[i]; d = ei[N_EDGES + i]; }
    else             { s = d = i - N_EDGES; }
    int pos = off[d] + atomicAdd(&cur[d], 1);
    csr_src[pos] = s;
}

// ---------------- graph boundaries (batch is sorted): no atomics ----------------

__global__ void k_bounds(const int* __restrict__ batch, int* __restrict__ gstart) {
    int i = blockIdx.x * blockDim.x + threadIdx.x;
    if (i >= N_NODES) return;
    int b = batch[i];
    int prev = (i == 0) ? -1 : batch[i - 1];
    for (int g = prev + 1; g <= b; ++g) gstart[g] = i;
    if (i == N_NODES - 1) {
        for (int g = b + 1; g <= NGRAPH; ++g) gstart[g] = N_NODES;
    }
}

// ---------------- W pre-swizzle: gat_W fp32 -> bf16 MFMA-fragment order ----------------

__global__ void k_wconv(const float* __restrict__ W, unsigned short* __restrict__ wswz) {
    int o = blockIdx.x * 256 + threadIdx.x;
    if (o >= LAYERS * 32 * 4 * 64 * 8) return;
    int e    = o & 7;
    int lane = (o >> 3) & 63;
    int kc   = (o >> 9) & 3;
    int cg   = (o >> 11) & 31;
    int l    = o >> 16;
    int k    = kc * 32 + (lane >> 4) * 8 + e;
    int col  = cg * 16 + (lane & 15);
    wswz[o] = f2bf(W[((size_t)l * HID + k) * FTOT + col]);
}

// ---------------- input projection: h = relu(x @ W_in + b_in), + bf16 shadow ----------------

__global__ __launch_bounds__(256) void k_inproj(const float* __restrict__ x,
                                                const float* __restrict__ W,
                                                const float* __restrict__ b,
                                                float* __restrict__ h,
                                                unsigned short* __restrict__ hb) {
    __shared__ float xs[2][F_IN];
    int tid = threadIdx.x;
    int node0 = blockIdx.x * 2;
    if (tid < 2 * F_IN) {
        int r = tid / F_IN, k = tid % F_IN;
        int nd = node0 + r;
        xs[r][k] = (nd < N_NODES) ? x[nd * F_IN + k] : 0.f;
    }
    __syncthreads();
    int ln = tid >> 7;
    int c  = tid & 127;
    int node = node0 + ln;
    if (node >= N_NODES) return;
    float s = b[c];
    #pragma unroll
    for (int k = 0; k < F_IN; ++k) s += xs[ln][k] * W[k * HID + c];
    float r = fmaxf(s, 0.f);
    h[(size_t)node * HID + c] = r;
    hb[(size_t)node * HID + c] = f2bf(r);
}

// ---------------- GEMM (MFMA) + fused attention dots ----------------
// grid (N_PAD/64, HEADS); block 256 = 4 waves; wave w: rows [bx*64+w*16,+16),
// cols [hd*128, +128). al_s/al_d written by plain stores.

__global__ __launch_bounds__(256) void k_gemm(const unsigned short* __restrict__ hb,
                                              const unsigned short* __restrict__ wswz,
                                              const float* __restrict__ asrc,
                                              const float* __restrict__ adst,
                                              unsigned short* __restrict__ xl,
                                              float* __restrict__ al_s,
                                              float* __restrict__ al_d) {
    int tid  = threadIdx.x;
    int lane = tid & 63;
    int w    = tid >> 6;
    int r0   = blockIdx.x * 64 + w * 16;
    int hd   = blockIdx.y;
    int arow = r0 + (lane & 15);
    const short8* ap = (const short8*)(hb + (size_t)arow * HID + (lane >> 4) * 8);
    const short8* bp = (const short8*)wswz;
    short8 a[4];
    #pragma unroll
    for (int kc = 0; kc < 4; ++kc) a[kc] = ap[kc * 4];   // kc*32 channels
    f32x4 acc[8];
    #pragma unroll
    for (int ct = 0; ct < 8; ++ct) {
        f32x4 c = {0.f, 0.f, 0.f, 0.f};
        int cg = hd * 8 + ct;
        #pragma unroll
        for (int kc = 0; kc < 4; ++kc) {
            short8 b = bp[(cg * 4 + kc) * 64 + lane];
            c = __builtin_amdgcn_mfma_f32_16x16x32_bf16(a[kc], b, c, 0, 0, 0);
        }
        acc[ct] = c;
    }
    int ocol = lane & 15;
    int orow = r0 + (lane >> 4) * 4;
    float vs[4] = {}, vd[4] = {};
    #pragma unroll
    for (int ct = 0; ct < 8; ++ct) {
        int colg = hd * 128 + ct * 16 + ocol;
        float as = asrc[colg], ad = adst[colg];
        #pragma unroll
        for (int r = 0; r < 4; ++r) {
            vs[r] += acc[ct][r] * as;
            vd[r] += acc[ct][r] * ad;
            int row = orow + r;
            if (row < N_NODES) xl[(size_t)row * FTOT + colg] = f2bf(acc[ct][r]);
        }
    }
    #pragma unroll
    for (int msk = 1; msk < 16; msk <<= 1) {
        #pragma unroll
        for (int r = 0; r < 4; ++r) {
            vs[r] += __shfl_xor(vs[r], msk, 64);
            vd[r] += __shfl_xor(vd[r], msk, 64);
        }
    }
    if (ocol == 0) {
        #pragma unroll
        for (int r = 0; r < 4; ++r) {
            int row = orow + r;
            if (row < N_NODES) {
                al_s[row * HEADS + hd] = vs[r];
                al_d[row * HEADS + hd] = vd[r];
            }
        }
    }
}

// ---------------- edge aggregation ----------------
// 1 wave per node (4 nodes/block). Pass A: 16 edge-lanes x 4 head-groups
// compute ev, butterfly (m,z), store p=exp(ev-m) to LDS. Pass B: pure gather,
// 4-deep unrolled (4 x 1KB rows in flight per wave); zinv in epilogue.

__global__ __launch_bounds__(256) void k_agg(const unsigned short* __restrict__ xl,
                                             const float* __restrict__ al_s,
                                             const float* __restrict__ al_d,
                                             const int* __restrict__ csr_off,
                                             const int* __restrict__ csr_src,
                                             const float* __restrict__ bias,
                                             float* __restrict__ h,
                                             unsigned short* __restrict__ hb) {
    __shared__ float alds[4][DEG_CAP][HEADS];   // [node][edge][head]
    int tid  = threadIdx.x;
    int lane = tid & 63;
    int wid  = tid >> 6;
    int node = blockIdx.x * 4 + wid;
    if (node >= N_NODES) return;
    int hh = lane >> 4;
    int el = lane & 15;
    int e0 = csr_off[node], e1 = csr_off[node + 1];
    int deg = e1 - e0;
    float ald = al_d[node * HEADS + hh];

    // ---- pass A ----
    float ev0 = -1e30f, ev1 = -1e30f, ev2 = -1e30f, ev3 = -1e30f;
    if (el < deg) {
        int s = csr_src[e0 + el];
        float e = al_s[s * HEADS + hh] + ald;
        ev0 = e > 0.f ? e : NEG_SLOPE * e;
    }
    if (el + 16 < deg) {
        int s = csr_src[e0 + el + 16];
        float e = al_s[s * HEADS + hh] + ald;
        ev1 = e > 0.f ? e : NEG_SLOPE * e;
    }
    if (el + 32 < deg) {
        int s = csr_src[e0 + el + 32];
        float e = al_s[s * HEADS + hh] + ald;
        ev2 = e > 0.f ? e : NEG_SLOPE * e;
    }
    if (el + 48 < deg) {
        int s = csr_src[e0 + el + 48];
        float e = al_s[s * HEADS + hh] + ald;
        ev3 = e > 0.f ? e : NEG_SLOPE * e;
    }
    float m = fmaxf(fmaxf(ev0, ev1), fmaxf(ev2, ev3));
    float z = 0.f;
    if (el      < deg) z += __expf(ev0 - m);
    if (el + 16 < deg) z += __expf(ev1 - m);
    if (el + 32 < deg) z += __expf(ev2 - m);
    if (el + 48 < deg) z += __expf(ev3 - m);
    for (int i = el + DEG_CAP; i < deg; i += 16) {   // rare tail
        int s = csr_src[e0 + i];
        float e = al_s[s * HEADS + hh] + ald;
        e = e > 0.f ? e : NEG_SLOPE * e;
        float mn = fmaxf(m, e);
        z = z * __expf(m - mn) + __expf(e - mn);
        m = mn;
    }
    #pragma unroll
    for (int msk = 1; msk < 16; msk <<= 1) {
        float m2 = __shfl_xor(m, msk, 64);
        float z2 = __shfl_xor(z, msk, 64);
        float mn = fmaxf(m, m2);
        z = z * __expf(m - mn) + z2 * __expf(m2 - mn);
        m = mn;
    }
    float zinv = 1.f / (z + 1e-16f);
    if (el      < deg) alds[wid][el     ][hh] = __expf(ev0 - m);
    if (el + 16 < deg) alds[wid][el + 16][hh] = __expf(ev1 - m);
    if (el + 32 < deg) alds[wid][el + 32][hh] = __expf(ev2 - m);
    if (el + 48 < deg) alds[wid][el + 48][hh] = __expf(ev3 - m);
    __syncthreads();

    // ---- pass B: 4-deep pipelined gather, 16 B/lane/edge ----
    float acc[8] = {};
    const unsigned short* xbase = xl + lane * 8;
    int dcap = deg < DEG_CAP ? deg : DEG_CAP;
    int i = 0;
    for (; i + 3 < dcap; i += 4) {
        int s0 = csr_src[e0 + i];
        int s1 = csr_src[e0 + i + 1];
        int s2 = csr_src[e0 + i + 2];
        int s3 = csr_src[e0 + i + 3];
        float a0 = alds[wid][i][hh];
        float a1 = alds[wid][i + 1][hh];
        float a2 = alds[wid][i + 2][hh];
        float a3 = alds[wid][i + 3][hh];
        ushortx8 v0 = *(const ushortx8*)(xbase + (size_t)s0 * FTOT);
        ushortx8 v1 = *(const ushortx8*)(xbase + (size_t)s1 * FTOT);
        ushortx8 v2 = *(const ushortx8*)(xbase + (size_t)s2 * FTOT);
        ushortx8 v3 = *(const ushortx8*)(xbase + (size_t)s3 * FTOT);
        #pragma unroll
        for (int j = 0; j < 8; ++j)
            acc[j] += (a0 * bf2f(v0[j]) + a1 * bf2f(v1[j]))
                    + (a2 * bf2f(v2[j]) + a3 * bf2f(v3[j]));
    }
    for (; i < dcap; ++i) {
        int s0 = csr_src[e0 + i];
        float a0 = alds[wid][i][hh];
        ushortx8 v0 = *(const ushortx8*)(xbase + (size_t)s0 * FTOT);
        #pragma unroll
        for (int j = 0; j < 8; ++j) acc[j] += a0 * bf2f(v0[j]);
    }
    for (int t = DEG_CAP; t < deg; ++t) {       // rare tail
        int s0 = csr_src[e0 + t];
        float e = al_s[s0 * HEADS + hh] + ald;
        e = e > 0.f ? e : NEG_SLOPE * e;
        float a0 = __expf(e - m);
        ushortx8 v0 = *(const ushortx8*)(xbase + (size_t)s0 * FTOT);
        #pragma unroll
        for (int j = 0; j < 8; ++j) acc[j] += a0 * bf2f(v0[j]);
    }
    #pragma unroll
    for (int j = 0; j < 8; ++j) {
        acc[j] *= zinv;
        acc[j] += __shfl_xor(acc[j], 16, 64);
        acc[j] += __shfl_xor(acc[j], 32, 64);
    }
    if (lane < 16) {
        int c = lane * 8;
        float4 hv0 = *(const float4*)(h + (size_t)node * HID + c);
        float4 hv1 = *(const float4*)(h + (size_t)node * HID + c + 4);
        float4 b0 = *(const float4*)(bias + c);
        float4 b1 = *(const float4*)(bias + c + 4);
        float o0 = fmaxf(acc[0] * 0.25f + b0.x, 0.f) + hv0.x;
        float o1 = fmaxf(acc[1] * 0.25f + b0.y, 0.f) + hv0.y;
        float o2 = fmaxf(acc[2] * 0.25f + b0.z, 0.f) + hv0.z;
        float o3 = fmaxf(acc[3] * 0.25f + b0.w, 0.f) + hv0.w;
        float o4 = fmaxf(acc[4] * 0.25f + b1.x, 0.f) + hv1.x;
        float o5 = fmaxf(acc[5] * 0.25f + b1.y, 0.f) + hv1.y;
        float o6 = fmaxf(acc[6] * 0.25f + b1.z, 0.f) + hv1.z;
        float o7 = fmaxf(acc[7] * 0.25f + b1.w, 0.f) + hv1.w;
        *(float4*)(h + (size_t)node * HID + c)     = make_float4(o0, o1, o2, o3);
        *(float4*)(h + (size_t)node * HID + c + 4) = make_float4(o4, o5, o6, o7);
        ushortx8 hv;
        hv[0] = f2bf(o0); hv[1] = f2bf(o1); hv[2] = f2bf(o2); hv[3] = f2bf(o3);
        hv[4] = f2bf(o4); hv[5] = f2bf(o5); hv[6] = f2bf(o6); hv[7] = f2bf(o7);
        *(ushortx8*)(hb + (size_t)node * HID + c) = hv;
    }
}

// ---------------- pooling + MLP ----------------

__global__ __launch_bounds__(128) void k_pool(const float* __restrict__ h,
                                              const int* __restrict__ gstart,
                                              float* __restrict__ pooled) {
    int g = blockIdx.y;
    int slice = blockIdx.x;      // 0..31
    int tid = threadIdx.x;       // 0..127
    int start = gstart[g];
    int cnt   = gstart[g + 1] - start;
    int per = (cnt + 31) / 32;
    int r0 = slice * per, r1 = min(r0 + per, cnt);
    if (r0 >= r1) return;
    float s0 = 0.f, s1 = 0.f, s2 = 0.f, s3 = 0.f;
    int r = r0;
    for (; r + 3 < r1; r += 4) {
        s0 += h[(size_t)(start + r)     * HID + tid];
        s1 += h[(size_t)(start + r + 1) * HID + tid];
        s2 += h[(size_t)(start + r + 2) * HID + tid];
        s3 += h[(size_t)(start + r + 3) * HID + tid];
    }
    for (; r < r1; ++r) s0 += h[(size_t)(start + r) * HID + tid];
    atomicAdd(&pooled[g * HID + tid], (s0 + s1) + (s2 + s3));
}

__global__ __launch_bounds__(256) void k_mlp(const float* __restrict__ pooled,
                                             const int* __restrict__ gstart,
                                             const float* __restrict__ W1, const float* __restrict__ b1,
                                             const float* __restrict__ W2, const float* __restrict__ b2,
                                             const float* __restrict__ W3, const float* __restrict__ b3,
                                             float* __restrict__ out) {
    int gr = blockIdx.x;
    __shared__ float g[HID];
    __shared__ float part[4][64];
    __shared__ float t1[64], t2[64];
    int tid = threadIdx.x;
    if (tid < HID) {
        float inv = 1.f / fmaxf((float)(gstart[gr + 1] - gstart[gr]), 1.f);
        g[tid] = pooled[gr * HID + tid] * inv;
    }
    __syncthreads();
    {
        int c = tid & 63, q = tid >> 6;
        float s = 0.f;
        #pragma unroll 8
        for (int k = q * 32; k < q * 32 + 32; ++k) s += g[k] * W1[k * 64 + c];
        part[q][c] = s;
        __syncthreads();
        if (tid < 64) t1[tid] = fmaxf(part[0][tid] + part[1][tid] + part[2][tid] + part[3][tid] + b1[tid], 0.f);
        __syncthreads();
    }
    {
        int c = tid & 63, q = tid >> 6;
        float s = 0.f;
        #pragma unroll 8
        for (int k = q * 16; k < q * 16 + 16; ++k) s += t1[k] * W2[k * 64 + c];
        part[q][c] = s;
        __syncthreads();
        if (tid < 64) t2[tid] = fmaxf(part[0][tid] + part[1][tid] + part[2][tid] + part[3][tid] + b2[tid], 0.f);
        __syncthreads();
    }
    {
        int c = tid & 31, q = tid >> 5;
        float s = 0.f;
        #pragma unroll 8
        for (int k = q * 8; k < q * 8 + 8; ++k) s += t2[k] * W3[k * 32 + c];
        float* pf = &part[0][0];
        pf[q * 32 + c] = s;
        __syncthreads();
        if (tid < 32) {
            float r = b3[tid];
            #pragma unroll
            for (int q2 = 0; q2 < 8; ++q2) r += pf[q2 * 32 + tid];
            out[gr * 32 + tid] = r;
        }
    }
}

// ---------------- launcher ----------------

extern "C" void kernel_launch(void* const* d_in, const int* in_sizes, int n_in,
                              void* d_out, int out_size, void* d_ws, size_t ws_size,
                              hipStream_t stream) {
    const float* x       = (const float*)d_in[0];
    const int*   ei      = (const int*)d_in[1];
    const int*   batch   = (const int*)d_in[2];
    const float* W_in    = (const float*)d_in[3];
    const float* b_in    = (const float*)d_in[4];
    const float* gat_W   = (const float*)d_in[5];
    const float* att_src = (const float*)d_in[6];
    const float* att_dst = (const float*)d_in[7];
    const float* gat_b   = (const float*)d_in[8];
    const float* W1 = (const float*)d_in[9];
    const float* b1 = (const float*)d_in[10];
    const float* W2 = (const float*)d_in[11];
    const float* b2 = (const float*)d_in[12];
    const float* W3 = (const float*)d_in[13];
    const float* b3 = (const float*)d_in[14];
    float* out = (float*)d_out;

    char* ws = (char*)d_ws;
    size_t o = 0;
    auto alloc = [&](size_t nbytes) -> void* {
        void* p = ws + o;
        o += (nbytes + 255) & ~(size_t)255;
        return p;
    };
    int* deg      = (int*)alloc((size_t)2 * N_NODES * 4);      // deg | cur
    int* cur      = deg + N_NODES;
    int* gstart   = (int*)alloc((size_t)(NGRAPH + 1) * 4);
    float* pooled = (float*)alloc((size_t)NGRAPH * HID * 4);
    int* csr_off  = (int*)alloc((size_t)(N_NODES + 1) * 4);
    int* csr_src  = (int*)alloc((size_t)ETOT * 4);
    float* h      = (float*)alloc((size_t)N_NODES * HID * 4);
    unsigned short* hb   = (unsigned short*)alloc((size_t)N_PAD * HID * 2);
    unsigned short* xl   = (unsigned short*)alloc((size_t)N_NODES * FTOT * 2);
    unsigned short* wswz = (unsigned short*)alloc((size_t)LAYERS * HID * FTOT * 2);
    float* al_s   = (float*)alloc((size_t)N_NODES * HEADS * 4);
    float* al_d   = (float*)alloc((size_t)N_NODES * HEADS * 4);

    hipMemsetAsync(deg, 0, (size_t)2 * N_NODES * 4, stream);
    hipMemsetAsync(pooled, 0, (size_t)NGRAPH * HID * 4, stream);

    k_hist<<<(ETOT + 255) / 256, 256, 0, stream>>>(ei, deg);
    k_scan<<<1, 1024, 0, stream>>>(deg, csr_off);
    k_scatter<<<(ETOT + 255) / 256, 256, 0, stream>>>(ei, csr_off, cur, csr_src);
    k_bounds<<<(N_NODES + 255) / 256, 256, 0, stream>>>(batch, gstart);
    k_wconv<<<(LAYERS * 32 * 4 * 64 * 8) / 256, 256, 0, stream>>>(gat_W, wswz);

    k_inproj<<<(N_NODES + 1) / 2, 256, 0, stream>>>(x, W_in, b_in, h, hb);

    for (int l = 0; l < LAYERS; ++l) {
        k_gemm<<<dim3(N_PAD / 64, HEADS), 256, 0, stream>>>(
            hb, wswz + (size_t)l * HID * FTOT,
            att_src + (size_t)l * HEADS * HID, att_dst + (size_t)l * HEADS * HID,
            xl, al_s, al_d);
        k_agg<<<(N_NODES + 3) / 4, 256, 0, stream>>>(
            xl, al_s, al_d, csr_off, csr_src, gat_b + (size_t)l * HID, h, hb);
    }

    k_pool<<<dim3(32, NGRAPH), 128, 0, stream>>>(h, gstart, pooled);
    k_mlp<<<NGRAPH, 256, 0, stream>>>(pooled, gstart, W1, b1, W2, b2, W3, b3, out);
}